// Round 1
// baseline (217.017 us; speedup 1.0000x reference)
//
#include <hip/hip_runtime.h>
#include <stdint.h>

#define DEV __device__ __forceinline__

typedef __bf16 bf16x8 __attribute__((ext_vector_type(8)));
typedef float  f32x4  __attribute__((ext_vector_type(4)));
typedef short  s16x8  __attribute__((ext_vector_type(8)));

constexpr int Bb   = 2;
constexpr int Nn   = 2048;
constexpr int DIMc = 1024;
constexpr int Hh   = 16;
constexpr int DHc  = 64;
constexpr int BN   = Bb * Nn;        // 4096
constexpr int QKVC = 3 * Hh * DHc;   // 3072

// f32 -> bf16 (RNE)
DEV ushort f2b(float f) {
  uint32_t u = __float_as_uint(f);
  u += 0x7fffu + ((u >> 16) & 1u);
  return (ushort)(u >> 16);
}

// async global->LDS, 16B per lane. LDS dest must be wave-uniform base (+lane*16 implicit).
DEV void gload16(const void* g, void* l) {
  __builtin_amdgcn_global_load_lds(
      (const __attribute__((address_space(1))) void*)(uintptr_t)g,
      (__attribute__((address_space(3))) void*)(uint32_t)(uintptr_t)l,
      16, 0, 0);
}

DEV f32x4 mfma16(bf16x8 a, bf16x8 b, f32x4 c) {
  return __builtin_amdgcn_mfma_f32_16x16x32_bf16(a, b, c, 0, 0, 0);
}

// ---------------- prep kernels ----------------

__global__ void k_cast_x(const float* __restrict__ x, ushort* __restrict__ xb) {
  int i = blockIdx.x * 256 + threadIdx.x;      // 524288 threads, 8 elems each
  size_t base = (size_t)i * 8;
  s16x8 v;
#pragma unroll
  for (int j = 0; j < 8; ++j) v[j] = (short)f2b(x[base + j]);
  *(s16x8*)(xb + base) = v;
}

__global__ void k_sincos(const float* __restrict__ rope,
                         float* __restrict__ cosT, float* __restrict__ sinT) {
  int i = blockIdx.x * 256 + threadIdx.x;      // N*DH = 131072
  float t = rope[i];
  float s, c;
  sincosf(t, &s, &c);
  cosT[i] = c;
  sinT[i] = s;
}

// dst[n][k] = (bf16) src[k][n]   (src: K x Ncols f32, dst: Ncols x K bf16)
__global__ void k_transpose_cast(const float* __restrict__ src, ushort* __restrict__ dst,
                                 int K, int Ncols) {
  __shared__ float tile[32][33];
  int nb = blockIdx.x * 32, kb = blockIdx.y * 32;
  int tx = threadIdx.x, ty = threadIdx.y;      // 32 x 8
#pragma unroll
  for (int i = 0; i < 4; ++i) {
    int k = ty + i * 8;
    tile[k][tx] = src[(size_t)(kb + k) * Ncols + nb + tx];
  }
  __syncthreads();
#pragma unroll
  for (int i = 0; i < 4; ++i) {
    int n = ty + i * 8;
    dst[(size_t)(nb + n) * K + kb + tx] = f2b(tile[tx][n]);
  }
}

// ---------------- GEMM core: C[128x128] = A[128xK] * Bt[128xK]^T, K=1024 ----------------
// 256 thr = 4 waves (2x2), each wave 64x64 = 4x4 frags of 16x16, K-step 32.
DEV void gemm_core(const ushort* __restrict__ A, const ushort* __restrict__ Bt,
                   int rowBase, int colBase, ushort* lA, ushort* lB,
                   f32x4 (&acc)[4][4]) {
  const int tid = threadIdx.x;
  const int lane = tid & 63, w = tid >> 6;
  const int wm = w >> 1, wn = w & 1;
  const int g = lane >> 4, l16 = lane & 15;
  const f32x4 zero = {0.f, 0.f, 0.f, 0.f};
#pragma unroll
  for (int i = 0; i < 4; ++i)
#pragma unroll
    for (int j = 0; j < 4; ++j) acc[i][j] = zero;

  for (int k0 = 0; k0 < DIMc; k0 += 32) {
#pragma unroll
    for (int s = 0; s < 2; ++s) {
      int c = s * 256 + tid;
      int row = c >> 2, kc = c & 3;            // tile row, 16B chunk in row (BK=32 -> 4 chunks)
      gload16(A  + (size_t)(rowBase + row) * DIMc + k0 + kc * 8,
              lA + (size_t)(s * 256 + w * 64) * 8);
      gload16(Bt + (size_t)(colBase + row) * DIMc + k0 + kc * 8,
              lB + (size_t)(s * 256 + w * 64) * 8);
    }
    __syncthreads();
    bf16x8 af[4], bfr[4];
#pragma unroll
    for (int f = 0; f < 4; ++f)
      af[f] = *(const bf16x8*)&lA[(wm * 64 + f * 16 + l16) * 32 + g * 8];
#pragma unroll
    for (int f = 0; f < 4; ++f)
      bfr[f] = *(const bf16x8*)&lB[(wn * 64 + f * 16 + l16) * 32 + g * 8];
#pragma unroll
    for (int i = 0; i < 4; ++i)
#pragma unroll
      for (int j = 0; j < 4; ++j)
        acc[i][j] = mfma16(af[i], bfr[j], acc[i][j]);
    __syncthreads();
  }
}

// ---------------- GEMM1: qkv = xb @ wqkvT^T, fused rotary; writes Q,K (b,h,n,d) and V^T (b,h,d,n) ----------------
__global__ __launch_bounds__(256) void k_gemm_qkv(
    const ushort* __restrict__ xb, const ushort* __restrict__ wT,
    const float* __restrict__ cosT, const float* __restrict__ sinT,
    ushort* __restrict__ Qd, ushort* __restrict__ Kd, ushort* __restrict__ Vd) {
  __shared__ ushort lA[128 * 32];
  __shared__ ushort lB[128 * 32];
  f32x4 acc[4][4];
  const int rowBase = blockIdx.y * 128, colBase = blockIdx.x * 128;
  gemm_core(xb, wT, rowBase, colBase, lA, lB, acc);

  const int lane = threadIdx.x & 63, w = threadIdx.x >> 6;
  const int wm = w >> 1, wn = w & 1;
  const int g = lane >> 4, l16 = lane & 15;
#pragma unroll
  for (int fm = 0; fm < 4; ++fm) {
#pragma unroll
    for (int fn = 0; fn < 4; ++fn) {
      int col = colBase + wn * 64 + fn * 16 + l16;   // 0..3071
      int sel = col >> 10, hc = col & 1023;
      int h = hc >> 6, d = hc & 63;
      float sgn = (d & 1) ? 1.f : -1.f;              // rotate_half sign
#pragma unroll
      for (int r = 0; r < 4; ++r) {
        float t  = acc[fm][fn][r];
        float tp = __shfl_xor(t, 1);                 // partner column (d^1)
        int row = rowBase + wm * 64 + fm * 16 + 4 * g + r;  // 0..4095
        int b = row >> 11, n = row & 2047;
        float cv = cosT[n * 64 + d], sv = sinT[n * 64 + d];
        float rv = t * cv + sgn * tp * sv;
        if (sel == 0) {
          Qd[((size_t)(b * Hh + h) * Nn + n) * DHc + d] = f2b(rv * 0.125f);
        } else if (sel == 1) {
          Kd[((size_t)(b * Hh + h) * Nn + n) * DHc + d] = f2b(rv);
        } else {
          Vd[((size_t)(b * Hh + h) * DHc + d) * Nn + n] = f2b(rv);  // V transposed
        }
      }
    }
  }
}

// ---------------- attention: flash-style, causal ----------------
// grid (N/64, B*H); block 256 = 4 waves, each wave 16 q-rows. K/V tiles 64x64 in LDS,
// XOR chunk-swizzle (both sides: pre-swizzled global src for global_load_lds, swizzled reads).
__global__ __launch_bounds__(256) void k_attn(
    const ushort* __restrict__ Qd, const ushort* __restrict__ Kd,
    const ushort* __restrict__ Vd, ushort* __restrict__ ao) {
  __shared__ ushort lK[64 * 64];
  __shared__ ushort lV[64 * 64];
  __shared__ ushort lP[4][16 * 64];
  const int tid = threadIdx.x;
  const int lane = tid & 63, w = tid >> 6;
  const int g = lane >> 4, l16 = lane & 15;
  const int bh = blockIdx.y;
  const int qBase = blockIdx.x * 64;
  const ushort* Qh = Qd + (size_t)bh * Nn * DHc;
  const ushort* Kh = Kd + (size_t)bh * Nn * DHc;
  const ushort* Vh = Vd + (size_t)bh * DHc * Nn;   // [d][n]

  // Q fragments live in registers: A-operand layout (row = lane&15, k = 8*(lane>>4)+j)
  bf16x8 q_a[2];
#pragma unroll
  for (int d0 = 0; d0 < 2; ++d0)
    q_a[d0] = *(const bf16x8*)(Qh + (size_t)(qBase + w * 16 + l16) * DHc + d0 * 32 + g * 8);

  const f32x4 zero = {0.f, 0.f, 0.f, 0.f};
  f32x4 o[4];
  float mrow[4], lrow[4];
#pragma unroll
  for (int dt = 0; dt < 4; ++dt) o[dt] = zero;
#pragma unroll
  for (int r = 0; r < 4; ++r) { mrow[r] = -3.0e38f; lrow[r] = 0.f; }

  const int nkt = blockIdx.x + 1;   // causal: k-tiles 0..blockIdx.x
  for (int kt = 0; kt < nkt; ++kt) {
    // stage K[j][d] and Vt[d][j] tiles (64x64 bf16 = 8 chunks/row), swizzled source
#pragma unroll
    for (int s = 0; s < 2; ++s) {
      int c = s * 256 + tid;
      int row = c >> 3, jst = c & 7;
      int jl = jst ^ (row & 7);                     // inverse swizzle on global source
      gload16(Kh + (size_t)(kt * 64 + row) * DHc + jl * 8,
              lK + (size_t)(s * 256 + w * 64) * 8);
      gload16(Vh + (size_t)row * Nn + kt * 64 + jl * 8,
              lV + (size_t)(s * 256 + w * 64) * 8);
    }
    __syncthreads();

    // S = Q K^T  (16 q-rows x 64 j per wave)
    f32x4 sacc[4];
#pragma unroll
    for (int jt = 0; jt < 4; ++jt) sacc[jt] = zero;
#pragma unroll
    for (int jt = 0; jt < 4; ++jt) {
      int jr = jt * 16 + l16;
#pragma unroll
      for (int d0 = 0; d0 < 2; ++d0) {
        int ch = d0 * 4 + g;
        bf16x8 kb = *(const bf16x8*)&lK[jr * 64 + ((ch ^ (jr & 7)) << 3)];
        sacc[jt] = mfma16(q_a[d0], kb, sacc[jt]);
      }
    }

    // causal mask + online softmax (rows m = 4g+r, cols jt*16+l16)
#pragma unroll
    for (int jt = 0; jt < 4; ++jt) {
      int jg = kt * 64 + jt * 16 + l16;
#pragma unroll
      for (int r = 0; r < 4; ++r) {
        int qg = qBase + w * 16 + 4 * g + r;
        if (jg > qg) sacc[jt][r] = -3.0e38f;
      }
    }
#pragma unroll
    for (int r = 0; r < 4; ++r) {
      float tmax = fmaxf(fmaxf(sacc[0][r], sacc[1][r]), fmaxf(sacc[2][r], sacc[3][r]));
      tmax = fmaxf(tmax, __shfl_xor(tmax, 1));
      tmax = fmaxf(tmax, __shfl_xor(tmax, 2));
      tmax = fmaxf(tmax, __shfl_xor(tmax, 4));
      tmax = fmaxf(tmax, __shfl_xor(tmax, 8));
      float mnew = fmaxf(mrow[r], tmax);
      float sc = __expf(mrow[r] - mnew);
      float ps = 0.f;
#pragma unroll
      for (int jt = 0; jt < 4; ++jt) {
        float p = __expf(sacc[jt][r] - mnew);
        sacc[jt][r] = p;
        ps += p;
      }
      ps += __shfl_xor(ps, 1);
      ps += __shfl_xor(ps, 2);
      ps += __shfl_xor(ps, 4);
      ps += __shfl_xor(ps, 8);
      lrow[r] = lrow[r] * sc + ps;
      mrow[r] = mnew;
#pragma unroll
      for (int dt = 0; dt < 4; ++dt) o[dt][r] *= sc;
    }

    // write P (bf16) to per-wave LDS, swizzled, D-layout -> A-layout transpose
    ushort* lPw = lP[w];
#pragma unroll
    for (int jt = 0; jt < 4; ++jt)
#pragma unroll
      for (int r = 0; r < 4; ++r) {
        int m = 4 * g + r;
        int j = jt * 16 + l16;
        lPw[m * 64 + (((j >> 3) ^ (m & 7)) << 3) + (j & 7)] = f2b(sacc[jt][r]);
      }
    __syncthreads();

    // O += P V   (A = P[16x64], B = Vt-tile read as contiguous k)
    bf16x8 pa[2];
#pragma unroll
    for (int jh = 0; jh < 2; ++jh) {
      int ch = jh * 4 + g;
      pa[jh] = *(const bf16x8*)&lPw[l16 * 64 + ((ch ^ (l16 & 7)) << 3)];
    }
#pragma unroll
    for (int dt = 0; dt < 4; ++dt) {
#pragma unroll
      for (int jh = 0; jh < 2; ++jh) {
        int d = dt * 16 + l16;
        int ch = jh * 4 + g;
        bf16x8 vb = *(const bf16x8*)&lV[d * 64 + ((ch ^ (d & 7)) << 3)];
        o[dt] = mfma16(pa[jh], vb, o[dt]);
      }
    }
    __syncthreads();
  }

  // epilogue: O / l -> ao[(b*N+n)][h*64+d]  (bf16)
  const int b = bh >> 4, h = bh & 15;
#pragma unroll
  for (int dt = 0; dt < 4; ++dt)
#pragma unroll
    for (int r = 0; r < 4; ++r) {
      float val = o[dt][r] / lrow[r];
      int n = qBase + w * 16 + 4 * g + r;
      int col = h * 64 + dt * 16 + l16;
      ao[(size_t)(b * Nn + n) * (Hh * DHc) + col] = f2b(val);
    }
}

// ---------------- GEMM2: out = ao @ woutT^T + bias (f32 out) ----------------
__global__ __launch_bounds__(256) void k_gemm_out(
    const ushort* __restrict__ ao, const ushort* __restrict__ wT,
    const float* __restrict__ bias, float* __restrict__ out) {
  __shared__ ushort lA[128 * 32];
  __shared__ ushort lB[128 * 32];
  f32x4 acc[4][4];
  const int rowBase = blockIdx.y * 128, colBase = blockIdx.x * 128;
  gemm_core(ao, wT, rowBase, colBase, lA, lB, acc);

  const int lane = threadIdx.x & 63, w = threadIdx.x >> 6;
  const int wm = w >> 1, wn = w & 1;
  const int g = lane >> 4, l16 = lane & 15;
#pragma unroll
  for (int fm = 0; fm < 4; ++fm)
#pragma unroll
    for (int fn = 0; fn < 4; ++fn) {
      int col = colBase + wn * 64 + fn * 16 + l16;
#pragma unroll
      for (int r = 0; r < 4; ++r) {
        int row = rowBase + wm * 64 + fm * 16 + 4 * g + r;
        out[(size_t)row * DIMc + col] = acc[fm][fn][r] + bias[col];
      }
    }
}

// ---------------- launch ----------------
extern "C" void kernel_launch(void* const* d_in, const int* in_sizes, int n_in,
                              void* d_out, int out_size, void* d_ws, size_t ws_size,
                              hipStream_t stream) {
  const float* x     = (const float*)d_in[0];
  const float* rope  = (const float*)d_in[1];
  const float* w_qkv = (const float*)d_in[2];
  const float* w_out = (const float*)d_in[3];
  const float* b_out = (const float*)d_in[4];
  float* out = (float*)d_out;

  char* ws = (char*)d_ws;
  ushort* xb    = (ushort*)(ws);              //  8 MB  x as bf16 (4096x1024)
  ushort* wqkvT = (ushort*)(ws + 8388608);    //  6 MB  w_qkv^T bf16 (3072x1024)
  ushort* woutT = (ushort*)(ws + 14680064);   //  2 MB  w_out^T bf16 (1024x1024)
  float*  cosT  = (float*) (ws + 16777216);   // 0.5 MB
  float*  sinT  = (float*) (ws + 17301504);   // 0.5 MB
  ushort* Qd    = (ushort*)(ws + 17825792);   //  8 MB  (b,h,n,d)
  ushort* Kd    = (ushort*)(ws + 26214400);   //  8 MB  (b,h,n,d)
  ushort* Vd    = (ushort*)(ws + 34603008);   //  8 MB  (b,h,d,n)  V^T
  ushort* ao    = (ushort*)(ws + 42991616);   //  8 MB  attn out (4096x1024)

  hipLaunchKernelGGL(k_cast_x, dim3(2048), dim3(256), 0, stream, x, xb);
  hipLaunchKernelGGL(k_transpose_cast, dim3(QKVC / 32, DIMc / 32), dim3(32, 8), 0, stream,
                     w_qkv, wqkvT, DIMc, QKVC);
  hipLaunchKernelGGL(k_transpose_cast, dim3(DIMc / 32, DIMc / 32), dim3(32, 8), 0, stream,
                     w_out, woutT, DIMc, DIMc);
  hipLaunchKernelGGL(k_sincos, dim3(Nn * DHc / 256), dim3(256), 0, stream, rope, cosT, sinT);
  hipLaunchKernelGGL(k_gemm_qkv, dim3(QKVC / 128, BN / 128), dim3(256), 0, stream,
                     xb, wqkvT, cosT, sinT, Qd, Kd, Vd);
  hipLaunchKernelGGL(k_attn, dim3(Nn / 64, Bb * Hh), dim3(256), 0, stream, Qd, Kd, Vd, ao);
  hipLaunchKernelGGL(k_gemm_out, dim3(DIMc / 128, BN / 128), dim3(256), 0, stream,
                     ao, woutT, b_out, out);
}

// Round 2
// 138.012 us; speedup vs baseline: 1.5725x; 1.5725x over previous
//
#include <hip/hip_runtime.h>
#include <stdint.h>

#define DEV __device__ __forceinline__

typedef __bf16 bf16x8 __attribute__((ext_vector_type(8)));
typedef float  f32x4  __attribute__((ext_vector_type(4)));
typedef short  s16x8  __attribute__((ext_vector_type(8)));

constexpr int Bb   = 2;
constexpr int Nn   = 2048;
constexpr int DIMc = 1024;
constexpr int Hh   = 16;
constexpr int DHc  = 64;
constexpr int BN   = Bb * Nn;        // 4096
constexpr int QKVC = 3 * Hh * DHc;   // 3072

// f32 -> bf16 (RNE)
DEV ushort f2b(float f) {
  uint32_t u = __float_as_uint(f);
  u += 0x7fffu + ((u >> 16) & 1u);
  return (ushort)(u >> 16);
}

// async global->LDS, 16B per lane. LDS dest must be wave-uniform base (+lane*16 implicit).
DEV void gload16(const void* g, void* l) {
  __builtin_amdgcn_global_load_lds(
      (const __attribute__((address_space(1))) void*)(uintptr_t)g,
      (__attribute__((address_space(3))) void*)(uint32_t)(uintptr_t)l,
      16, 0, 0);
}

DEV f32x4 mfma16(bf16x8 a, bf16x8 b, f32x4 c) {
  return __builtin_amdgcn_mfma_f32_16x16x32_bf16(a, b, c, 0, 0, 0);
}

DEV uint32_t cvtpk(float lo, float hi) {
  uint32_t r;
  asm("v_cvt_pk_bf16_f32 %0, %1, %2" : "=v"(r) : "v"(lo), "v"(hi));
  return r;
}

// ---------------- prep kernels ----------------

__global__ void k_cast_x(const float* __restrict__ x, ushort* __restrict__ xb) {
  int i = blockIdx.x * 256 + threadIdx.x;
  size_t base = (size_t)i * 8;
  s16x8 v;
#pragma unroll
  for (int j = 0; j < 8; ++j) v[j] = (short)f2b(x[base + j]);
  *(s16x8*)(xb + base) = v;
}

__global__ void k_sincos(const float* __restrict__ rope,
                         float* __restrict__ cosT, float* __restrict__ sinT) {
  int i = blockIdx.x * 256 + threadIdx.x;
  float t = rope[i];
  float s, c;
  sincosf(t, &s, &c);
  cosT[i] = c;
  sinT[i] = s;
}

__global__ void k_transpose_cast(const float* __restrict__ src, ushort* __restrict__ dst,
                                 int K, int Ncols) {
  __shared__ float tile[32][33];
  int nb = blockIdx.x * 32, kb = blockIdx.y * 32;
  int tx = threadIdx.x, ty = threadIdx.y;
#pragma unroll
  for (int i = 0; i < 4; ++i) {
    int k = ty + i * 8;
    tile[k][tx] = src[(size_t)(kb + k) * Ncols + nb + tx];
  }
  __syncthreads();
#pragma unroll
  for (int i = 0; i < 4; ++i) {
    int n = ty + i * 8;
    dst[(size_t)(nb + n) * K + kb + tx] = f2b(tile[tx][n]);
  }
}

// ---------------- GEMM core (unchanged from R1) ----------------
DEV void gemm_core(const ushort* __restrict__ A, const ushort* __restrict__ Bt,
                   int rowBase, int colBase, ushort* lA, ushort* lB,
                   f32x4 (&acc)[4][4]) {
  const int tid = threadIdx.x;
  const int lane = tid & 63, w = tid >> 6;
  const int wm = w >> 1, wn = w & 1;
  const int g = lane >> 4, l16 = lane & 15;
  const f32x4 zero = {0.f, 0.f, 0.f, 0.f};
#pragma unroll
  for (int i = 0; i < 4; ++i)
#pragma unroll
    for (int j = 0; j < 4; ++j) acc[i][j] = zero;

  for (int k0 = 0; k0 < DIMc; k0 += 32) {
#pragma unroll
    for (int s = 0; s < 2; ++s) {
      int c = s * 256 + tid;
      int row = c >> 2, kc = c & 3;
      gload16(A  + (size_t)(rowBase + row) * DIMc + k0 + kc * 8,
              lA + (size_t)(s * 256 + w * 64) * 8);
      gload16(Bt + (size_t)(colBase + row) * DIMc + k0 + kc * 8,
              lB + (size_t)(s * 256 + w * 64) * 8);
    }
    __syncthreads();
    bf16x8 af[4], bfr[4];
#pragma unroll
    for (int f = 0; f < 4; ++f)
      af[f] = *(const bf16x8*)&lA[(wm * 64 + f * 16 + l16) * 32 + g * 8];
#pragma unroll
    for (int f = 0; f < 4; ++f)
      bfr[f] = *(const bf16x8*)&lB[(wn * 64 + f * 16 + l16) * 32 + g * 8];
#pragma unroll
    for (int i = 0; i < 4; ++i)
#pragma unroll
      for (int j = 0; j < 4; ++j)
        acc[i][j] = mfma16(af[i], bfr[j], acc[i][j]);
    __syncthreads();
  }
}

// ---------------- GEMM1 (unchanged) ----------------
__global__ __launch_bounds__(256) void k_gemm_qkv(
    const ushort* __restrict__ xb, const ushort* __restrict__ wT,
    const float* __restrict__ cosT, const float* __restrict__ sinT,
    ushort* __restrict__ Qd, ushort* __restrict__ Kd, ushort* __restrict__ Vd) {
  __shared__ ushort lA[128 * 32];
  __shared__ ushort lB[128 * 32];
  f32x4 acc[4][4];
  const int rowBase = blockIdx.y * 128, colBase = blockIdx.x * 128;
  gemm_core(xb, wT, rowBase, colBase, lA, lB, acc);

  const int lane = threadIdx.x & 63, w = threadIdx.x >> 6;
  const int wm = w >> 1, wn = w & 1;
  const int g = lane >> 4, l16 = lane & 15;
#pragma unroll
  for (int fm = 0; fm < 4; ++fm) {
#pragma unroll
    for (int fn = 0; fn < 4; ++fn) {
      int col = colBase + wn * 64 + fn * 16 + l16;
      int sel = col >> 10, hc = col & 1023;
      int h = hc >> 6, d = hc & 63;
      float sgn = (d & 1) ? 1.f : -1.f;
#pragma unroll
      for (int r = 0; r < 4; ++r) {
        float t  = acc[fm][fn][r];
        float tp = __shfl_xor(t, 1);
        int row = rowBase + wm * 64 + fm * 16 + 4 * g + r;
        int b = row >> 11, n = row & 2047;
        float cv = cosT[n * 64 + d], sv = sinT[n * 64 + d];
        float rv = t * cv + sgn * tp * sv;
        if (sel == 0) {
          Qd[((size_t)(b * Hh + h) * Nn + n) * DHc + d] = f2b(rv * 0.125f);
        } else if (sel == 1) {
          Kd[((size_t)(b * Hh + h) * Nn + n) * DHc + d] = f2b(rv);
        } else {
          Vd[((size_t)(b * Hh + h) * DHc + d) * Nn + n] = f2b(rv);
        }
      }
    }
  }
}

// ---------------- attention v2: swapped QK^T, lane-local softmax, paired q-tiles, dbuf K/V ----------------

DEV void stageKV(const ushort* __restrict__ Kh, const ushort* __restrict__ Vh,
                 ushort* lKb, ushort* lVb, int kt, int tid, int w) {
#pragma unroll
  for (int s = 0; s < 2; ++s) {
    int c = s * 256 + tid;
    int row = c >> 3, jst = c & 7;
    int jl = jst ^ (row & 7);                  // inverse swizzle on global source
    gload16(Kh + (size_t)(kt * 64 + row) * DHc + jl * 8,
            lKb + (size_t)(s * 256 + w * 64) * 8);
    gload16(Vh + (size_t)row * Nn + kt * 64 + jl * 8,
            lVb + (size_t)(s * 256 + w * 64) * 8);
  }
}

// one 64-wide k-tile for one q-tile (16 q-rows per wave; this lane owns q-row i=l16)
DEV void attn_step(const ushort* lKc, const ushort* lVc, char* lPw,
                   const bf16x8 (&q)[2], f32x4 (&o)[4], float& m, float& l,
                   int kBase, int qg, bool diag, int g, int l16) {
  const f32x4 zero = {0.f, 0.f, 0.f, 0.f};
  f32x4 s[4];
#pragma unroll
  for (int jt = 0; jt < 4; ++jt) s[jt] = zero;

  // S^T = K * Q^T : D[j][i], lane holds col i=l16, rows j=jt*16+4g+r
#pragma unroll
  for (int jt = 0; jt < 4; ++jt) {
    int jr = jt * 16 + l16;                    // A-frag row (j) for this lane
#pragma unroll
    for (int d0 = 0; d0 < 2; ++d0) {
      bf16x8 kb = *(const bf16x8*)&lKc[jr * 64 + (((d0 * 4 + g) ^ (jr & 7)) << 3)];
      s[jt] = mfma16(kb, q[d0], s[jt]);
    }
  }

  if (diag) {
#pragma unroll
    for (int jt = 0; jt < 4; ++jt)
#pragma unroll
      for (int r = 0; r < 4; ++r) {
        int j = kBase + jt * 16 + 4 * g + r;
        if (j > qg) s[jt][r] = -3.0e38f;
      }
  }

  // lane-local row max over 16 values + reduce across the 4 g-lanes of this row
  float tmax = fmaxf(fmaxf(fmaxf(s[0][0], s[0][1]), fmaxf(s[0][2], s[0][3])),
                     fmaxf(fmaxf(s[1][0], s[1][1]), fmaxf(s[1][2], s[1][3])));
  tmax = fmaxf(tmax, fmaxf(fmaxf(fmaxf(s[2][0], s[2][1]), fmaxf(s[2][2], s[2][3])),
                           fmaxf(fmaxf(s[3][0], s[3][1]), fmaxf(s[3][2], s[3][3]))));
  tmax = fmaxf(tmax, __shfl_xor(tmax, 16));
  tmax = fmaxf(tmax, __shfl_xor(tmax, 32));

  // defer-max (T13): skip rescale when max grew < 8
  if (!__all(tmax <= m + 8.f)) {
    float mnew = fmaxf(m, tmax);
    float sc = __expf(m - mnew);
#pragma unroll
    for (int dt = 0; dt < 4; ++dt) o[dt] *= sc;
    l *= sc;
    m = mnew;
  }

  float ps = 0.f;
#pragma unroll
  for (int jt = 0; jt < 4; ++jt)
#pragma unroll
    for (int r = 0; r < 4; ++r) {
      float p = __expf(s[jt][r] - m);
      s[jt][r] = p;
      ps += p;
    }
  ps += __shfl_xor(ps, 16);
  ps += __shfl_xor(ps, 32);
  l += ps;

  // P store: row i=l16 of Pst[i][j], packed bf16x2 words, XOR-swizzled (per-wave buffer, no barrier)
  const int sw = (l16 & 7) << 4;
  char* prow = lPw + l16 * 128;
#pragma unroll
  for (int jt = 0; jt < 4; ++jt) {
    int jo = (jt * 16 + 4 * g) * 2;            // byte offset of word0
    *(uint32_t*)(prow + (jo ^ sw))       = cvtpk(s[jt][0], s[jt][1]);
    *(uint32_t*)(prow + ((jo + 4) ^ sw)) = cvtpk(s[jt][2], s[jt][3]);
  }

  // O^T += V^T * P : A=V^T rows d, B=P cols i; D[d][i], lane holds col i=l16, rows d=dt*16+4g+r
  bf16x8 pa[2];
#pragma unroll
  for (int jh = 0; jh < 2; ++jh)
    pa[jh] = *(const bf16x8*)(prow + (((jh * 32 + 8 * g) * 2) ^ sw));
#pragma unroll
  for (int dt = 0; dt < 4; ++dt) {
    int d = dt * 16 + l16;
#pragma unroll
    for (int jh = 0; jh < 2; ++jh) {
      bf16x8 vb = *(const bf16x8*)&lVc[d * 64 + (((jh * 4 + g) ^ (d & 7)) << 3)];
      o[dt] = mfma16(vb, pa[jh], o[dt]);
    }
  }
}

DEV void attn_epi(ushort* __restrict__ ao, int bh, int n, int g,
                  f32x4 (&o)[4], float l) {
  const int b = bh >> 4, h = bh & 15;
  float inv = 1.f / l;
  ushort* dst = ao + (size_t)(b * Nn + n) * (Hh * DHc) + h * 64;
#pragma unroll
  for (int dt = 0; dt < 4; ++dt) {
    uint2 pkd;
    pkd.x = cvtpk(o[dt][0] * inv, o[dt][1] * inv);
    pkd.y = cvtpk(o[dt][2] * inv, o[dt][3] * inv);
    *(uint2*)(dst + dt * 16 + 4 * g) = pkd;
  }
}

// grid (16, B*H); block 256 = 4 waves. Block owns q-tiles {p, 31-p} (uniform 33 compute-iters).
__global__ __launch_bounds__(256) void k_attn(
    const ushort* __restrict__ Qd, const ushort* __restrict__ Kd,
    const ushort* __restrict__ Vd, ushort* __restrict__ ao) {
  __shared__ ushort lK[2][64 * 64];
  __shared__ ushort lV[2][64 * 64];
  __shared__ char   lP[4][16 * 128];
  const int tid = threadIdx.x;
  const int lane = tid & 63, w = tid >> 6;
  const int g = lane >> 4, l16 = lane & 15;
  const int bh = blockIdx.y;
  const int p = blockIdx.x;                    // 0..15
  const int tA = p, tB = 31 - p;
  const int last = tB;                         // k-tiles 0..last
  const ushort* Qh = Qd + (size_t)bh * Nn * DHc;
  const ushort* Kh = Kd + (size_t)bh * Nn * DHc;
  const ushort* Vh = Vd + (size_t)bh * DHc * Nn;

  const int qgA = tA * 64 + w * 16 + l16;
  const int qgB = tB * 64 + w * 16 + l16;

  bf16x8 qA[2], qB[2];
#pragma unroll
  for (int d0 = 0; d0 < 2; ++d0) {
    qA[d0] = *(const bf16x8*)(Qh + (size_t)qgA * DHc + d0 * 32 + g * 8);
    qB[d0] = *(const bf16x8*)(Qh + (size_t)qgB * DHc + d0 * 32 + g * 8);
  }

  const f32x4 zero = {0.f, 0.f, 0.f, 0.f};
  f32x4 oA[4], oB[4];
#pragma unroll
  for (int dt = 0; dt < 4; ++dt) { oA[dt] = zero; oB[dt] = zero; }
  float mA = -3.0e38f, lA_ = 0.f, mB = -3.0e38f, lB_ = 0.f;

  stageKV(Kh, Vh, lK[0], lV[0], 0, tid, w);

  for (int kt = 0; kt <= last; ++kt) {
    const int cur = kt & 1;
    if (kt < last) {
      stageKV(Kh, Vh, lK[cur ^ 1], lV[cur ^ 1], kt + 1, tid, w);
      asm volatile("s_waitcnt vmcnt(4)" ::: "memory");   // drain current buf's 4 loads, keep next 4 in flight
    } else {
      asm volatile("s_waitcnt vmcnt(0)" ::: "memory");
    }
    __builtin_amdgcn_s_barrier();

    attn_step(lK[cur], lV[cur], lP[w], qB, oB, mB, lB_, kt * 64, qgB, kt == tB, g, l16);
    if (kt <= tA)
      attn_step(lK[cur], lV[cur], lP[w], qA, oA, mA, lA_, kt * 64, qgA, kt == tA, g, l16);

    __builtin_amdgcn_s_barrier();              // all waves done reading buf[cur] before it is re-staged
  }

  attn_epi(ao, bh, qgA, g, oA, lA_);
  attn_epi(ao, bh, qgB, g, oB, lB_);
}

// ---------------- GEMM2 (unchanged) ----------------
__global__ __launch_bounds__(256) void k_gemm_out(
    const ushort* __restrict__ ao, const ushort* __restrict__ wT,
    const float* __restrict__ bias, float* __restrict__ out) {
  __shared__ ushort lA[128 * 32];
  __shared__ ushort lB[128 * 32];
  f32x4 acc[4][4];
  const int rowBase = blockIdx.y * 128, colBase = blockIdx.x * 128;
  gemm_core(ao, wT, rowBase, colBase, lA, lB, acc);

  const int lane = threadIdx.x & 63, w = threadIdx.x >> 6;
  const int wm = w >> 1, wn = w & 1;
  const int g = lane >> 4, l16 = lane & 15;
#pragma unroll
  for (int fm = 0; fm < 4; ++fm)
#pragma unroll
    for (int fn = 0; fn < 4; ++fn) {
      int col = colBase + wn * 64 + fn * 16 + l16;
#pragma unroll
      for (int r = 0; r < 4; ++r) {
        int row = rowBase + wm * 64 + fm * 16 + 4 * g + r;
        out[(size_t)row * DIMc + col] = acc[fm][fn][r] + bias[col];
      }
    }
}

// ---------------- launch ----------------
extern "C" void kernel_launch(void* const* d_in, const int* in_sizes, int n_in,
                              void* d_out, int out_size, void* d_ws, size_t ws_size,
                              hipStream_t stream) {
  const float* x     = (const float*)d_in[0];
  const float* rope  = (const float*)d_in[1];
  const float* w_qkv = (const float*)d_in[2];
  const float* w_out = (const float*)d_in[3];
  const float* b_out = (const float*)d_in[4];
  float* out = (float*)d_out;

  char* ws = (char*)d_ws;
  ushort* xb    = (ushort*)(ws);
  ushort* wqkvT = (ushort*)(ws + 8388608);
  ushort* woutT = (ushort*)(ws + 14680064);
  float*  cosT  = (float*) (ws + 16777216);
  float*  sinT  = (float*) (ws + 17301504);
  ushort* Qd    = (ushort*)(ws + 17825792);
  ushort* Kd    = (ushort*)(ws + 26214400);
  ushort* Vd    = (ushort*)(ws + 34603008);
  ushort* ao    = (ushort*)(ws + 42991616);

  hipLaunchKernelGGL(k_cast_x, dim3(2048), dim3(256), 0, stream, x, xb);
  hipLaunchKernelGGL(k_transpose_cast, dim3(QKVC / 32, DIMc / 32), dim3(32, 8), 0, stream,
                     w_qkv, wqkvT, DIMc, QKVC);
  hipLaunchKernelGGL(k_transpose_cast, dim3(DIMc / 32, DIMc / 32), dim3(32, 8), 0, stream,
                     w_out, woutT, DIMc, DIMc);
  hipLaunchKernelGGL(k_sincos, dim3(Nn * DHc / 256), dim3(256), 0, stream, rope, cosT, sinT);
  hipLaunchKernelGGL(k_gemm_qkv, dim3(QKVC / 128, BN / 128), dim3(256), 0, stream,
                     xb, wqkvT, cosT, sinT, Qd, Kd, Vd);
  hipLaunchKernelGGL(k_attn, dim3(16, Bb * Hh), dim3(256), 0, stream, Qd, Kd, Vd, ao);
  hipLaunchKernelGGL(k_gemm_out, dim3(DIMc / 128, BN / 128), dim3(256), 0, stream,
                     ao, woutT, b_out, out);
}

// Round 3
// 135.594 us; speedup vs baseline: 1.6005x; 1.0178x over previous
//
#include <hip/hip_runtime.h>
#include <stdint.h>

#define DEV __device__ __forceinline__

typedef __bf16 bf16x8 __attribute__((ext_vector_type(8)));
typedef float  f32x4  __attribute__((ext_vector_type(4)));
typedef short  s16x8  __attribute__((ext_vector_type(8)));

constexpr int Bb   = 2;
constexpr int Nn   = 2048;
constexpr int DIMc = 1024;
constexpr int Hh   = 16;
constexpr int DHc  = 64;
constexpr int BN   = Bb * Nn;        // 4096
constexpr int QKVC = 3 * Hh * DHc;   // 3072

// f32 -> bf16 (RNE)
DEV ushort f2b(float f) {
  uint32_t u = __float_as_uint(f);
  u += 0x7fffu + ((u >> 16) & 1u);
  return (ushort)(u >> 16);
}

// async global->LDS, 16B per lane. LDS dest must be wave-uniform base (+lane*16 implicit).
DEV void gload16(const void* g, void* l) {
  __builtin_amdgcn_global_load_lds(
      (const __attribute__((address_space(1))) void*)(uintptr_t)g,
      (__attribute__((address_space(3))) void*)(uint32_t)(uintptr_t)l,
      16, 0, 0);
}

DEV f32x4 mfma16(bf16x8 a, bf16x8 b, f32x4 c) {
  return __builtin_amdgcn_mfma_f32_16x16x32_bf16(a, b, c, 0, 0, 0);
}

DEV uint32_t cvtpk(float lo, float hi) {
  uint32_t r;
  asm("v_cvt_pk_bf16_f32 %0, %1, %2" : "=v"(r) : "v"(lo), "v"(hi));
  return r;
}

// ---------------- prep kernels ----------------

__global__ void k_cast_x(const float* __restrict__ x, ushort* __restrict__ xb) {
  int i = blockIdx.x * 256 + threadIdx.x;
  size_t base = (size_t)i * 8;
  s16x8 v;
#pragma unroll
  for (int j = 0; j < 8; ++j) v[j] = (short)f2b(x[base + j]);
  *(s16x8*)(xb + base) = v;
}

__global__ void k_sincos(const float* __restrict__ rope, float2* __restrict__ csT) {
  int i = blockIdx.x * 256 + threadIdx.x;
  float t = rope[i];
  float s, c;
  sincosf(t, &s, &c);
  csT[i] = make_float2(c, s);
}

__global__ void k_transpose_cast(const float* __restrict__ src, ushort* __restrict__ dst,
                                 int K, int Ncols) {
  __shared__ float tile[32][33];
  int nb = blockIdx.x * 32, kb = blockIdx.y * 32;
  int tx = threadIdx.x, ty = threadIdx.y;
#pragma unroll
  for (int i = 0; i < 4; ++i) {
    int k = ty + i * 8;
    tile[k][tx] = src[(size_t)(kb + k) * Ncols + nb + tx];
  }
  __syncthreads();
#pragma unroll
  for (int i = 0; i < 4; ++i) {
    int n = ty + i * 8;
    dst[(size_t)(nb + n) * K + kb + tx] = f2b(tile[tx][n]);
  }
}

// ---------------- GEMM core v2: swizzled LDS + dbuf + counted vmcnt ----------------
// C[128x128] = A[128xK] * Bt[128xK]^T, K=1024, BK=32.
// LDS tile [128 rows][4 chunks of 16B]; phys chunk kc holds global chunk kc^((row>>1)&3)
// (inverse-swizzled global source for global_load_lds; same XOR on ds_read).
DEV void gemm_core(const ushort* __restrict__ A, const ushort* __restrict__ Bt,
                   int rowBase, int colBase, ushort* lA, ushort* lB,
                   f32x4 (&acc)[4][4]) {
  const int tid = threadIdx.x;
  const int lane = tid & 63, w = tid >> 6;
  const int wm = w >> 1, wn = w & 1;
  const int g = lane >> 4, l16 = lane & 15;
  const f32x4 zero = {0.f, 0.f, 0.f, 0.f};
#pragma unroll
  for (int i = 0; i < 4; ++i)
#pragma unroll
    for (int j = 0; j < 4; ++j) acc[i][j] = zero;

  // per-thread staging coords (constant across K-steps)
  const int c0row = tid >> 2,          c0kc = (tid & 3) ^ ((c0row >> 1) & 3);
  const int c1row = (256 + tid) >> 2,  c1kc = (tid & 3) ^ ((c1row >> 1) & 3);
  const ushort* gA0 = A  + (size_t)(rowBase + c0row) * DIMc + c0kc * 8;
  const ushort* gA1 = A  + (size_t)(rowBase + c1row) * DIMc + c1kc * 8;
  const ushort* gB0 = Bt + (size_t)(colBase + c0row) * DIMc + c0kc * 8;
  const ushort* gB1 = Bt + (size_t)(colBase + c1row) * DIMc + c1kc * 8;
  ushort* lDst0 = (ushort*)((size_t)(0 * 256 + w * 64) * 8 * 2);  // byte offsets within buffer
  const size_t o0 = (size_t)(0 * 256 + w * 64) * 8;
  const size_t o1 = (size_t)(1 * 256 + w * 64) * 8;

  // prologue: stage K-step 0 into buffer 0
  gload16(gA0, lA + o0);
  gload16(gB0, lB + o0);
  gload16(gA1, lA + o1);
  gload16(gB1, lB + o1);

  for (int k0 = 0; k0 < DIMc; k0 += 32) {
    const int cur = (k0 >> 5) & 1;
    ushort* cA = lA + cur * (128 * 32);
    ushort* cB = lB + cur * (128 * 32);
    if (k0 + 32 < DIMc) {
      ushort* nA = lA + (cur ^ 1) * (128 * 32);
      ushort* nB = lB + (cur ^ 1) * (128 * 32);
      int kn = k0 + 32;
      gload16(gA0 + kn, nA + o0);
      gload16(gB0 + kn, nB + o0);
      gload16(gA1 + kn, nA + o1);
      gload16(gB1 + kn, nB + o1);
      asm volatile("s_waitcnt vmcnt(4)" ::: "memory");   // current buf's 4 done; next 4 in flight
    } else {
      asm volatile("s_waitcnt vmcnt(0)" ::: "memory");
    }
    __builtin_amdgcn_s_barrier();

    bf16x8 af[4], bfr[4];
#pragma unroll
    for (int f = 0; f < 4; ++f) {
      int r  = wm * 64 + f * 16 + l16;
      int r2 = wn * 64 + f * 16 + l16;
      af[f]  = *(const bf16x8*)&cA[r * 32 + ((g ^ ((r >> 1) & 3)) << 3)];
      bfr[f] = *(const bf16x8*)&cB[r2 * 32 + ((g ^ ((r2 >> 1) & 3)) << 3)];
    }
#pragma unroll
    for (int i = 0; i < 4; ++i)
#pragma unroll
      for (int j = 0; j < 4; ++j)
        acc[i][j] = mfma16(af[i], bfr[j], acc[i][j]);

    __builtin_amdgcn_s_barrier();              // all waves done with buf[cur] before re-stage
  }
}

// ---------------- GEMM1: qkv = xb @ wqkvT^T, fused rotary ----------------
__global__ __launch_bounds__(256) void k_gemm_qkv(
    const ushort* __restrict__ xb, const ushort* __restrict__ wT,
    const float2* __restrict__ csT,
    ushort* __restrict__ Qd, ushort* __restrict__ Kd, ushort* __restrict__ Vd) {
  __shared__ ushort lA[2 * 128 * 32];
  __shared__ ushort lB[2 * 128 * 32];
  f32x4 acc[4][4];
  const int rowBase = blockIdx.y * 128, colBase = blockIdx.x * 128;
  gemm_core(xb, wT, rowBase, colBase, lA, lB, acc);

  const int lane = threadIdx.x & 63, w = threadIdx.x >> 6;
  const int wm = w >> 1, wn = w & 1;
  const int g = lane >> 4, l16 = lane & 15;
#pragma unroll
  for (int fm = 0; fm < 4; ++fm) {
#pragma unroll
    for (int fn = 0; fn < 4; ++fn) {
      int col = colBase + wn * 64 + fn * 16 + l16;
      int sel = col >> 10, hc = col & 1023;
      int h = hc >> 6, d = hc & 63;
      float sgn = (d & 1) ? 1.f : -1.f;
#pragma unroll
      for (int r = 0; r < 4; ++r) {
        float t  = acc[fm][fn][r];
        float tp = __shfl_xor(t, 1);
        int row = rowBase + wm * 64 + fm * 16 + 4 * g + r;
        int b = row >> 11, n = row & 2047;
        float2 cs = csT[n * 64 + d];
        float rv = t * cs.x + sgn * tp * cs.y;
        if (sel == 0) {
          Qd[((size_t)(b * Hh + h) * Nn + n) * DHc + d] = f2b(rv * 0.125f);
        } else if (sel == 1) {
          Kd[((size_t)(b * Hh + h) * Nn + n) * DHc + d] = f2b(rv);
        } else {
          Vd[((size_t)(b * Hh + h) * DHc + d) * Nn + n] = f2b(rv);
        }
      }
    }
  }
}

// ---------------- attention (unchanged from R2) ----------------

DEV void stageKV(const ushort* __restrict__ Kh, const ushort* __restrict__ Vh,
                 ushort* lKb, ushort* lVb, int kt, int tid, int w) {
#pragma unroll
  for (int s = 0; s < 2; ++s) {
    int c = s * 256 + tid;
    int row = c >> 3, jst = c & 7;
    int jl = jst ^ (row & 7);
    gload16(Kh + (size_t)(kt * 64 + row) * DHc + jl * 8,
            lKb + (size_t)(s * 256 + w * 64) * 8);
    gload16(Vh + (size_t)row * Nn + kt * 64 + jl * 8,
            lVb + (size_t)(s * 256 + w * 64) * 8);
  }
}

DEV void attn_step(const ushort* lKc, const ushort* lVc, char* lPw,
                   const bf16x8 (&q)[2], f32x4 (&o)[4], float& m, float& l,
                   int kBase, int qg, bool diag, int g, int l16) {
  const f32x4 zero = {0.f, 0.f, 0.f, 0.f};
  f32x4 s[4];
#pragma unroll
  for (int jt = 0; jt < 4; ++jt) s[jt] = zero;

#pragma unroll
  for (int jt = 0; jt < 4; ++jt) {
    int jr = jt * 16 + l16;
#pragma unroll
    for (int d0 = 0; d0 < 2; ++d0) {
      bf16x8 kb = *(const bf16x8*)&lKc[jr * 64 + (((d0 * 4 + g) ^ (jr & 7)) << 3)];
      s[jt] = mfma16(kb, q[d0], s[jt]);
    }
  }

  if (diag) {
#pragma unroll
    for (int jt = 0; jt < 4; ++jt)
#pragma unroll
      for (int r = 0; r < 4; ++r) {
        int j = kBase + jt * 16 + 4 * g + r;
        if (j > qg) s[jt][r] = -3.0e38f;
      }
  }

  float tmax = fmaxf(fmaxf(fmaxf(s[0][0], s[0][1]), fmaxf(s[0][2], s[0][3])),
                     fmaxf(fmaxf(s[1][0], s[1][1]), fmaxf(s[1][2], s[1][3])));
  tmax = fmaxf(tmax, fmaxf(fmaxf(fmaxf(s[2][0], s[2][1]), fmaxf(s[2][2], s[2][3])),
                           fmaxf(fmaxf(s[3][0], s[3][1]), fmaxf(s[3][2], s[3][3]))));
  tmax = fmaxf(tmax, __shfl_xor(tmax, 16));
  tmax = fmaxf(tmax, __shfl_xor(tmax, 32));

  if (!__all(tmax <= m + 8.f)) {
    float mnew = fmaxf(m, tmax);
    float sc = __expf(m - mnew);
#pragma unroll
    for (int dt = 0; dt < 4; ++dt) o[dt] *= sc;
    l *= sc;
    m = mnew;
  }

  float ps = 0.f;
#pragma unroll
  for (int jt = 0; jt < 4; ++jt)
#pragma unroll
    for (int r = 0; r < 4; ++r) {
      float p = __expf(s[jt][r] - m);
      s[jt][r] = p;
      ps += p;
    }
  ps += __shfl_xor(ps, 16);
  ps += __shfl_xor(ps, 32);
  l += ps;

  const int sw = (l16 & 7) << 4;
  char* prow = lPw + l16 * 128;
#pragma unroll
  for (int jt = 0; jt < 4; ++jt) {
    int jo = (jt * 16 + 4 * g) * 2;
    *(uint32_t*)(prow + (jo ^ sw))       = cvtpk(s[jt][0], s[jt][1]);
    *(uint32_t*)(prow + ((jo + 4) ^ sw)) = cvtpk(s[jt][2], s[jt][3]);
  }

  bf16x8 pa[2];
#pragma unroll
  for (int jh = 0; jh < 2; ++jh)
    pa[jh] = *(const bf16x8*)(prow + (((jh * 32 + 8 * g) * 2) ^ sw));
#pragma unroll
  for (int dt = 0; dt < 4; ++dt) {
    int d = dt * 16 + l16;
#pragma unroll
    for (int jh = 0; jh < 2; ++jh) {
      bf16x8 vb = *(const bf16x8*)&lVc[d * 64 + (((jh * 4 + g) ^ (d & 7)) << 3)];
      o[dt] = mfma16(vb, pa[jh], o[dt]);
    }
  }
}

DEV void attn_epi(ushort* __restrict__ ao, int bh, int n, int g,
                  f32x4 (&o)[4], float l) {
  const int b = bh >> 4, h = bh & 15;
  float inv = 1.f / l;
  ushort* dst = ao + (size_t)(b * Nn + n) * (Hh * DHc) + h * 64;
#pragma unroll
  for (int dt = 0; dt < 4; ++dt) {
    uint2 pkd;
    pkd.x = cvtpk(o[dt][0] * inv, o[dt][1] * inv);
    pkd.y = cvtpk(o[dt][2] * inv, o[dt][3] * inv);
    *(uint2*)(dst + dt * 16 + 4 * g) = pkd;
  }
}

__global__ __launch_bounds__(256) void k_attn(
    const ushort* __restrict__ Qd, const ushort* __restrict__ Kd,
    const ushort* __restrict__ Vd, ushort* __restrict__ ao) {
  __shared__ ushort lK[2][64 * 64];
  __shared__ ushort lV[2][64 * 64];
  __shared__ char   lP[4][16 * 128];
  const int tid = threadIdx.x;
  const int lane = tid & 63, w = tid >> 6;
  const int g = lane >> 4, l16 = lane & 15;
  const int bh = blockIdx.y;
  const int p = blockIdx.x;
  const int tA = p, tB = 31 - p;
  const int last = tB;
  const ushort* Qh = Qd + (size_t)bh * Nn * DHc;
  const ushort* Kh = Kd + (size_t)bh * Nn * DHc;
  const ushort* Vh = Vd + (size_t)bh * DHc * Nn;

  const int qgA = tA * 64 + w * 16 + l16;
  const int qgB = tB * 64 + w * 16 + l16;

  bf16x8 qA[2], qB[2];
#pragma unroll
  for (int d0 = 0; d0 < 2; ++d0) {
    qA[d0] = *(const bf16x8*)(Qh + (size_t)qgA * DHc + d0 * 32 + g * 8);
    qB[d0] = *(const bf16x8*)(Qh + (size_t)qgB * DHc + d0 * 32 + g * 8);
  }

  const f32x4 zero = {0.f, 0.f, 0.f, 0.f};
  f32x4 oA[4], oB[4];
#pragma unroll
  for (int dt = 0; dt < 4; ++dt) { oA[dt] = zero; oB[dt] = zero; }
  float mA = -3.0e38f, lA_ = 0.f, mB = -3.0e38f, lB_ = 0.f;

  stageKV(Kh, Vh, lK[0], lV[0], 0, tid, w);

  for (int kt = 0; kt <= last; ++kt) {
    const int cur = kt & 1;
    if (kt < last) {
      stageKV(Kh, Vh, lK[cur ^ 1], lV[cur ^ 1], kt + 1, tid, w);
      asm volatile("s_waitcnt vmcnt(4)" ::: "memory");
    } else {
      asm volatile("s_waitcnt vmcnt(0)" ::: "memory");
    }
    __builtin_amdgcn_s_barrier();

    attn_step(lK[cur], lV[cur], lP[w], qB, oB, mB, lB_, kt * 64, qgB, kt == tB, g, l16);
    if (kt <= tA)
      attn_step(lK[cur], lV[cur], lP[w], qA, oA, mA, lA_, kt * 64, qgA, kt == tA, g, l16);

    __builtin_amdgcn_s_barrier();
  }

  attn_epi(ao, bh, qgA, g, oA, lA_);
  attn_epi(ao, bh, qgB, g, oB, lB_);
}

// ---------------- GEMM2: out = ao @ woutT^T + bias (f32 out) ----------------
__global__ __launch_bounds__(256) void k_gemm_out(
    const ushort* __restrict__ ao, const ushort* __restrict__ wT,
    const float* __restrict__ bias, float* __restrict__ out) {
  __shared__ ushort lA[2 * 128 * 32];
  __shared__ ushort lB[2 * 128 * 32];
  f32x4 acc[4][4];
  const int rowBase = blockIdx.y * 128, colBase = blockIdx.x * 128;
  gemm_core(ao, wT, rowBase, colBase, lA, lB, acc);

  const int lane = threadIdx.x & 63, w = threadIdx.x >> 6;
  const int wm = w >> 1, wn = w & 1;
  const int g = lane >> 4, l16 = lane & 15;
#pragma unroll
  for (int fm = 0; fm < 4; ++fm)
#pragma unroll
    for (int fn = 0; fn < 4; ++fn) {
      int col = colBase + wn * 64 + fn * 16 + l16;
#pragma unroll
      for (int r = 0; r < 4; ++r) {
        int row = rowBase + wm * 64 + fm * 16 + 4 * g + r;
        out[(size_t)row * DIMc + col] = acc[fm][fn][r] + bias[col];
      }
    }
}

// ---------------- launch ----------------
extern "C" void kernel_launch(void* const* d_in, const int* in_sizes, int n_in,
                              void* d_out, int out_size, void* d_ws, size_t ws_size,
                              hipStream_t stream) {
  const float* x     = (const float*)d_in[0];
  const float* rope  = (const float*)d_in[1];
  const float* w_qkv = (const float*)d_in[2];
  const float* w_out = (const float*)d_in[3];
  const float* b_out = (const float*)d_in[4];
  float* out = (float*)d_out;

  char* ws = (char*)d_ws;
  ushort* xb    = (ushort*)(ws);
  ushort* wqkvT = (ushort*)(ws + 8388608);
  ushort* woutT = (ushort*)(ws + 14680064);
  float2* csT   = (float2*)(ws + 16777216);   // 1 MB (cos,sin interleaved)
  ushort* Qd    = (ushort*)(ws + 17825792);
  ushort* Kd    = (ushort*)(ws + 26214400);
  ushort* Vd    = (ushort*)(ws + 34603008);
  ushort* ao    = (ushort*)(ws + 42991616);

  hipLaunchKernelGGL(k_cast_x, dim3(2048), dim3(256), 0, stream, x, xb);
  hipLaunchKernelGGL(k_transpose_cast, dim3(QKVC / 32, DIMc / 32), dim3(32, 8), 0, stream,
                     w_qkv, wqkvT, DIMc, QKVC);
  hipLaunchKernelGGL(k_transpose_cast, dim3(DIMc / 32, DIMc / 32), dim3(32, 8), 0, stream,
                     w_out, woutT, DIMc, DIMc);
  hipLaunchKernelGGL(k_sincos, dim3(Nn * DHc / 256), dim3(256), 0, stream, rope, csT);
  hipLaunchKernelGGL(k_gemm_qkv, dim3(QKVC / 128, BN / 128), dim3(256), 0, stream,
                     xb, wqkvT, csT, Qd, Kd, Vd);
  hipLaunchKernelGGL(k_attn, dim3(16, Bb * Hh), dim3(256), 0, stream, Qd, Kd, Vd, ao);
  hipLaunchKernelGGL(k_gemm_out, dim3(DIMc / 128, BN / 128), dim3(256), 0, stream,
                     ao, woutT, b_out, out);
}